// Round 9
// baseline (73.880 us; speedup 1.0000x reference)
//
#include <hip/hip_runtime.h>
#include <hip/hip_bf16.h>
#include <math.h>

typedef short bf16x8 __attribute__((ext_vector_type(8)));
typedef float f32x4 __attribute__((ext_vector_type(4)));
typedef float f32x16 __attribute__((ext_vector_type(16)));
typedef unsigned short u16;
typedef unsigned long long u64;

#define AS1(p) ((const __attribute__((address_space(1))) unsigned int*)(p))
#define AS3(p) ((__attribute__((address_space(3))) unsigned int*)(p))

#define WAITVM2 asm volatile("s_waitcnt vmcnt(2)" ::: "memory")
#define WAITVM0 asm volatile("s_waitcnt vmcnt(0)" ::: "memory")
#define BARRIER asm volatile("s_barrier" ::: "memory")

__device__ __forceinline__ u16 f2bf(float f) {
  union { float f; unsigned u; } v; v.f = f;
  unsigned r = v.u + 0x7fffu + ((v.u >> 16) & 1u);  // RNE
  return (u16)(r >> 16);
}

// ---------- Kernel P: bit-pack adj + row degree (ballot, coalesced) ----------
// grid 4096 = 8 batches x 512 rowgroups (bid&7 = batch). 256 thr = 4 waves,
// 1 row per wave. Iter it: lane l reads adj[row][it*64+l] (dense 256B/instr);
// __ballot(v>0) = u64 mask of 64 consecutive cols; lane it keeps it.
// Store: lanes 0..31 write their u64 at slot l^(row&7) (pre-swizzle for
// k_agg's linear LDS copy + swizzled read). deg = sum of popcounts (exact).
__global__ __launch_bounds__(256) void k_pack(
    const float* __restrict__ adj, unsigned* __restrict__ bits, float* __restrict__ deg)
{
  const int b   = blockIdx.x & 7;
  const int rg  = blockIdx.x >> 3;        // 0..511
  const int wid = threadIdx.x >> 6;
  const int l   = threadIdx.x & 63;
  const int row = rg * 4 + wid;           // 0..2047
  const float* srcRow = adj + ((size_t)b * 2048 + row) * 2048;

  u64 mine = 0;
  float d = 0.f;
#pragma unroll
  for (int it = 0; it < 32; ++it) {
    const float v = srcRow[it * 64 + l];
    const u64 bal = __ballot(v > 0.f);
    d += (float)__popcll(bal);            // wave-uniform
    if (l == it) mine = bal;
  }
  u64* bitsRow = (u64*)(bits + ((size_t)b * 2048 + row) * 64);
  if (l < 32) bitsRow[l ^ (row & 7)] = mine;
  if (l == 0) deg[(size_t)b * 2048 + row] = d;
}

// ---------- Kernel 0: Wt[f][k] = bf16(W[k][f]) (256x256) ----------
__global__ void k_wt(const float* __restrict__ W, u16* __restrict__ Wt) {
  int idx = blockIdx.x * 256 + threadIdx.x;
#pragma unroll
  for (int q = 0; q < 4; ++q) {
    int i = idx + q * 16384;
    int f = i & 255, k = i >> 8;
    Wt[f * 256 + k] = f2bf(W[k * 256 + f]);
  }
}

// ---------- Kernel A: ht[b][f][j] = bf16( (x @ W)[b,j,f] ) ----------
// bid&7 = batch -> batch b's ht written by XCD-b blocks, stays in its L2.
__global__ __launch_bounds__(512, 4) void k_xw(
    const float* __restrict__ x, const u16* __restrict__ Wt, u16* __restrict__ ht)
{
  __shared__ u16 Ab[2][32 * 64];
  __shared__ u16 Bb[2][256 * 64];

  const int tid = threadIdx.x;
  const int lane = tid & 63;
  const int wid = tid >> 6;
  const int wr = wid >> 2, wc = wid & 3;

  const int b  = blockIdx.x & 7;
  const int jt = blockIdx.x >> 3;
  const int jloc = jt * 32;
  const float* xb = x + ((size_t)b * 2048 + jloc) * 256;
  u16* htb = ht + ((size_t)b << 19);

  const int ar = tid >> 4;
  const int ac = tid & 15;
  const int awb = ar * 128 + ((ac * 8) ^ ((ar & 7) << 4));

  f32x4 acc[4] = {};

  auto stage = [&](int t, int bufi) {
    const float4 v = *(const float4*)(xb + ar * 256 + t * 64 + ac * 4);
    short4 p;
    p.x = (short)f2bf(v.x); p.y = (short)f2bf(v.y);
    p.z = (short)f2bf(v.z); p.w = (short)f2bf(v.w);
    *(short4*)((char*)(&Ab[bufi][0]) + awb) = p;
#pragma unroll
    for (int q = 0; q < 4; ++q) {
      const int fbase = wid * 32 + q * 8;
      const int f = fbase + (lane >> 3);
      const char* src = (const char*)Wt + f * 512 + t * 128
                        + (((lane & 7) * 16) ^ ((f & 7) << 4));
      __builtin_amdgcn_global_load_lds(AS1(src),
          AS3((char*)(&Bb[bufi][0]) + fbase * 128), 16, 0, 0);
    }
  };

  auto compute = [&](int bufi) {
#pragma unroll
    for (int kk = 0; kk < 2; ++kk) {
      const int am = wr * 16 + (lane & 15);
      const bf16x8 a = *(const bf16x8*)((const char*)(&Ab[bufi][0])
          + am * 128 + ((kk * 64 + (lane >> 4) * 16) ^ ((am & 7) << 4)));
#pragma unroll
      for (int nf = 0; nf < 4; ++nf) {
        const int bn = wc * 64 + nf * 16 + (lane & 15);
        const bf16x8 bv = *(const bf16x8*)((const char*)(&Bb[bufi][0])
            + bn * 128 + ((kk * 64 + (lane >> 4) * 16) ^ ((bn & 7) << 4)));
        acc[nf] = __builtin_amdgcn_mfma_f32_16x16x32_bf16(a, bv, acc[nf], 0, 0, 0);
      }
    }
  };

  stage(0, 0);
  __syncthreads();
#pragma unroll 2
  for (int t = 0; t < 4; ++t) {
    const int cur = t & 1;
    if (t + 1 < 4) stage(t + 1, cur ^ 1);
    compute(cur);
    __syncthreads();
  }

  const int j0 = jloc + wr * 16 + ((lane >> 4) << 2);
#pragma unroll
  for (int nf = 0; nf < 4; ++nf) {
    const int f = wc * 64 + nf * 16 + (lane & 15);
    short4 p;
    p.x = (short)f2bf(acc[nf][0]);
    p.y = (short)f2bf(acc[nf][1]);
    p.z = (short)f2bf(acc[nf][2]);
    p.w = (short)f2bf(acc[nf][3]);
    *(short4*)(&htb[(size_t)f * 2048 + j0]) = p;
  }
}

// ---------- Kernel B: out = elu( (1/deg) * adj @ h ) ---------- (r8 verbatim)
__global__ __launch_bounds__(512, 1) void k_agg(
    const unsigned* __restrict__ bits, const float* __restrict__ deg,
    const u16* __restrict__ ht, float* __restrict__ out)
{
  __shared__ unsigned bitsLds[128 * 64];   // 32 KB, pre-swizzled 8B units
  __shared__ u16 Bbuf[3][128 * 64];        // 16 KB x3: ht [128f][64k], slot^(f&7)

  const int tid  = threadIdx.x;
  const int lane = tid & 63;
  const int wid  = tid >> 6;
  const int sm   = wid >> 1;          // 0..3: 32-row strip
  const int sn   = wid & 1;           // 0..1: 64-f strip

  const int b  = blockIdx.x & 7;
  const int rt = (blockIdx.x >> 3) & 15;
  const int nt = blockIdx.x >> 7;     // 0 or 1
  const int row0 = rt * 128;

  const char* bsrc = (const char*)(bits + ((size_t)b * 2048 + row0) * 64);
  const char* htB  = (const char*)ht + ((size_t)b << 20) + (size_t)nt * 524288;
  const float* degB = deg + (size_t)b * 2048 + row0;
  float* outb = out + ((size_t)b * 2048 + row0) * 256 + nt * 128;

#pragma unroll
  for (int q = 0; q < 4; ++q) {
    __builtin_amdgcn_global_load_lds(AS1(bsrc + q * 8192 + wid * 1024 + lane * 16),
        AS3((char*)bitsLds + q * 8192 + wid * 1024), 16, 0, 0);
  }

  auto stage = [&](int t, int r) {
#pragma unroll
    for (int q = 0; q < 2; ++q) {
      const int f = q * 64 + wid * 8 + (lane >> 3);
      const int s = lane & 7;
      const char* src = htB + (size_t)f * 4096 + (size_t)t * 128 + ((s ^ (f & 7)) * 16);
      __builtin_amdgcn_global_load_lds(AS1(src),
          AS3((char*)(&Bbuf[r][0]) + q * 8192 + wid * 1024), 16, 0, 0);
    }
  };

  f32x16 acc[2] = {};
  const int lo = lane & 31;
  const int hi = lane >> 5;
  const int arow = sm * 32 + lo;

  stage(0, 0);
  stage(1, 1);

  for (int t = 0; t < 32; ++t) {
    if (t < 31) { WAITVM2; } else { WAITVM0; }
    BARRIER;
    const int r = t % 3;
    if (t < 30) stage(t + 2, (t + 2) % 3);
    const u64 rowbits = *(const u64*)((const char*)bitsLds
        + arow * 256 + ((t ^ (arow & 7)) * 8));
    const char* Bb = (const char*)(&Bbuf[r][0]);
#pragma unroll
    for (int ksl = 0; ksl < 4; ++ksl) {
      const unsigned byte = (unsigned)(rowbits >> ((ksl * 2 + hi) * 8)) & 0xFFu;
      union { bf16x8 v; unsigned u[4]; } af;
#pragma unroll
      for (int w = 0; w < 4; ++w) {
        const unsigned l16 = ((byte >> (2 * w)) & 1u) * 0x3F80u;
        const unsigned h16 = ((byte >> (2 * w + 1)) & 1u) * 0x3F80u;
        af.u[w] = l16 | (h16 << 16);
      }
#pragma unroll
      for (int nf = 0; nf < 2; ++nf) {
        const int f = sn * 64 + nf * 32 + lo;
        const bf16x8 bv = *(const bf16x8*)(Bb + f * 128
            + (((ksl * 2 + hi) ^ (f & 7)) * 16));
        acc[nf] = __builtin_amdgcn_mfma_f32_32x32x16_bf16(af.v, bv, acc[nf], 0, 0, 0);
      }
    }
  }

#pragma unroll
  for (int reg = 0; reg < 16; ++reg) {
    const int rl = (reg & 3) + 8 * (reg >> 2) + 4 * hi;
    const float d = degB[sm * 32 + rl];
    const float sc = d > 0.f ? 1.f / d : (1.f / 2048.f);
    float* orow = outb + (size_t)(sm * 32 + rl) * 256 + sn * 64 + lo;
#pragma unroll
    for (int nf = 0; nf < 2; ++nf) {
      const float v = acc[nf][reg] * sc;
      orow[nf * 32] = v > 0.f ? v : expm1f(v);
    }
  }
}

extern "C" void kernel_launch(void* const* d_in, const int* in_sizes, int n_in,
                              void* d_out, int out_size, void* d_ws, size_t ws_size,
                              hipStream_t stream) {
  const float* x   = (const float*)d_in[0];
  const float* adj = (const float*)d_in[1];
  const float* W   = (const float*)d_in[2];
  // d_in[3] ('a') is mathematically dead: softmax rows are constant over the
  // active (adj>0) entries, so attention = 1/deg regardless of e.
  float* out = (float*)d_out;

  u16*      Wt   = (u16*)d_ws;                              // 128 KB
  u16*      ht   = (u16*)((char*)d_ws + 131072);            // 8 MB
  unsigned* bits = (unsigned*)((char*)d_ws + 8519680);      // 4 MB
  float*    degp = (float*)((char*)d_ws + 12713984);        // 64 KB

  // k_pack FIRST: its 134 MB adj stream must not evict ht from L2.
  k_pack<<<4096, 256, 0, stream>>>(adj, bits, degp);
  k_wt<<<64, 256, 0, stream>>>(W, Wt);
  k_xw<<<512, 512, 0, stream>>>(x, Wt, ht);
  k_agg<<<256, 512, 0, stream>>>(bits, degp, ht, out);
}